// Round 4
// baseline (4750.895 us; speedup 1.0000x reference)
//
#include <hip/hip_runtime.h>
#include <cmath>

#define Bc 32
#define Tc 32
#define Sc 64
#define Hc 512
#define Ec 512
#define Vc 32000
#define NEGC (-1e9f)
#define BH (Bc * Hc)
#define Mtot ((Tc - 1) * Bc)   // 992
#define NBLK 256

__device__ __forceinline__ float sigf(float x) { return 1.0f / (1.0f + expf(-x)); }

__device__ __forceinline__ float dot4(const float* a, const float* b) {
    float4 x = *(const float4*)a;
    float4 y = *(const float4*)b;
    return x.x * y.x + x.y * y.y + x.z * y.z + x.w * y.w;
}

// h slab0 = h0, ah slot0 = 0, barrier counter = 0
__global__ __launch_bounds__(256) void k_init(const float* __restrict__ h0,
                                              float* __restrict__ hG,
                                              float* __restrict__ ah0,
                                              unsigned* __restrict__ bar) {
    int i = blockIdx.x * 256 + threadIdx.x;
    if (i < BH) { hG[i] = h0[i]; ah0[i] = 0.0f; }
    if (i < 64) bar[i] = 0u;
}

// proj[b][s][k] = sum_h W_a[k][h] * enc[s][b][h]
__global__ __launch_bounds__(256) void k_proj(const float* __restrict__ W_a,
                                              const float* __restrict__ enc,
                                              float* __restrict__ proj) {
    int k = blockIdx.x * 256 + threadIdx.x;
    int s0 = blockIdx.y * 8;
    int b = blockIdx.z;
    __shared__ float se[8][Hc];
    for (int i = threadIdx.x; i < 8 * Hc; i += 256) {
        int ss = i >> 9, hh = i & (Hc - 1);
        se[ss][hh] = enc[((size_t)(s0 + ss) * Bc + b) * Hc + hh];
    }
    __syncthreads();
    const float* wr = W_a + (size_t)k * Hc;
    float acc[8];
#pragma unroll
    for (int ss = 0; ss < 8; ++ss) acc[ss] = 0.0f;
    for (int h = 0; h < Hc; h += 4) {
        float4 w = *(const float4*)(wr + h);
#pragma unroll
        for (int ss = 0; ss < 8; ++ss) {
            acc[ss] = fmaf(w.x, se[ss][h + 0], acc[ss]);
            acc[ss] = fmaf(w.y, se[ss][h + 1], acc[ss]);
            acc[ss] = fmaf(w.z, se[ss][h + 2], acc[ss]);
            acc[ss] = fmaf(w.w, se[ss][h + 3], acc[ss]);
        }
    }
#pragma unroll
    for (int ss = 0; ss < 8; ++ss)
        proj[((size_t)b * Sc + s0 + ss) * Hc + k] = acc[ss];
}

// Device-scope grid barrier: monotone counter, 256 arrivals per barrier.
#define GBAR(target)                                                                     \
    do {                                                                                 \
        __syncthreads();                                                                 \
        if (tid == 0) {                                                                  \
            __threadfence();                                                             \
            __hip_atomic_fetch_add(bar, 1u, __ATOMIC_RELEASE, __HIP_MEMORY_SCOPE_AGENT); \
            while (__hip_atomic_load(bar, __ATOMIC_ACQUIRE,                              \
                                     __HIP_MEMORY_SCOPE_AGENT) < (unsigned)(target))     \
                __builtin_amdgcn_s_sleep(2);                                             \
        }                                                                                \
        __syncthreads();                                                                 \
        __threadfence();                                                                 \
    } while (0)

// Persistent kernel (plain launch, custom barrier): all 31 recurrent steps.
// grid 256x256. Phase1: gates+LSTM, block owns h = bid*2+{0,1} (weights L1/L2-hot),
// c in registers. Phase2: block (b = bid&31, g = bid>>5): score+softmax+ctx
// (redundant per g; same-b blocks share an XCD since bid%8 is equal) + W_c rows
// [g*64, g*64+64) -> ah(t+1).
__global__ __launch_bounds__(256, 1) void k_loop(const int* __restrict__ tgt,
                                                 const float* __restrict__ emb,
                                                 const float* __restrict__ W_ih,
                                                 const float* __restrict__ W_hh,
                                                 const float* __restrict__ b_ih,
                                                 const float* __restrict__ b_hh,
                                                 const float* __restrict__ proj,
                                                 const float* __restrict__ enc,
                                                 const int* __restrict__ len_src,
                                                 const float* __restrict__ W_c,
                                                 const float* __restrict__ b_c,
                                                 const float* __restrict__ c0,
                                                 float* __restrict__ hG,
                                                 float* __restrict__ ah_all,
                                                 unsigned* __restrict__ bar) {
    int bid = blockIdx.x;
    int tid = threadIdx.x;

    // phase-1 identity
    int b1 = tid & 31;
    int q = (tid >> 5) & 3;
    int hl = tid >> 7;
    int h = bid * 2 + hl;
    int j = (q << 9) + h;
    const float* wi  = W_ih + (size_t)j * (Ec + Hc);       // x part [0,512)
    const float* wi2 = wi + Ec;                            // ah part [512,1024)
    const float* wh  = W_hh + (size_t)j * Hc;
    float bias = b_ih[j] + b_hh[j];
    float c_reg = (q == 0) ? c0[b1 * Hc + h] : 0.0f;

    // phase-2 identity
    int b2 = bid & 31;
    int g = bid >> 5;

    __shared__ float sg[2][4][32];
    __shared__ float shc[2 * Hc];   // [0,H)=h2  [H,2H)=ctx
    __shared__ float sraw[Sc];
    __shared__ float sal[Sc];

    for (int t = 0; t < Tc - 1; ++t) {
        const float* hR = hG + (t & 1) * BH;
        float* hW = hG + ((t + 1) & 1) * BH;

        // ---- phase 1: gates + LSTM ----
        {
            int w = tgt[b1 * Tc + t];
            const float* x = emb + (size_t)w * Ec;
            const float* ap = ah_all + (size_t)t * BH + b1 * Hc;
            const float* hp = hR + b1 * Hc;
            float a0 = 0.f, a1 = 0.f, a2 = 0.f, a3 = 0.f;
            for (int e = 0; e < Ec; e += 16) {
                a0 += dot4(x + e, wi + e);
                a1 += dot4(x + e + 4, wi + e + 4);
                a2 += dot4(x + e + 8, wi + e + 8);
                a3 += dot4(x + e + 12, wi + e + 12);
            }
            for (int k = 0; k < Hc; k += 16) {
                a0 += dot4(ap + k, wi2 + k);
                a1 += dot4(ap + k + 4, wi2 + k + 4);
                a2 += dot4(ap + k + 8, wi2 + k + 8);
                a3 += dot4(ap + k + 12, wi2 + k + 12);
            }
            for (int k = 0; k < Hc; k += 16) {
                a0 += dot4(hp + k, wh + k);
                a1 += dot4(hp + k + 4, wh + k + 4);
                a2 += dot4(hp + k + 8, wh + k + 8);
                a3 += dot4(hp + k + 12, wh + k + 12);
            }
            float acc = bias + ((a0 + a1) + (a2 + a3));
            sg[hl][q][b1] = acc;
            __syncthreads();
            if (q == 0) {
                float iv = sigf(sg[hl][0][b1]);
                float fv = sigf(sg[hl][1][b1]);
                float gv = tanhf(sg[hl][2][b1]);
                float ov = sigf(sg[hl][3][b1]);
                c_reg = fv * c_reg + iv * gv;
                hW[b1 * Hc + h] = ov * tanhf(c_reg);
            }
        }
        GBAR((2 * t + 1) * NBLK);

        // ---- phase 2: attention + W_c ----
        {
            for (int k = tid; k < Hc; k += 256) shc[k] = hW[b2 * Hc + k];
            __syncthreads();

            // scores
            {
                int s = tid >> 2, r = tid & 3;
                const float* pr = proj + ((size_t)b2 * Sc + s) * Hc + r * 128;
                const float* hh = shc + r * 128;
                float p0 = 0.f, p1 = 0.f;
                for (int k = 0; k < 128; k += 8) {
                    p0 += dot4(hh + k, pr + k);
                    p1 += dot4(hh + k + 4, pr + k + 4);
                }
                float p = p0 + p1;
                p += __shfl_xor(p, 1);
                p += __shfl_xor(p, 2);
                if (r == 0) sraw[s] = p;
            }
            __syncthreads();

            // masked softmax (wave 0)
            if (tid < Sc) {
                int len = len_src[b2];
                float sc = (tid < len) ? sraw[tid] : NEGC;
                float mx = sc;
#pragma unroll
                for (int m = 32; m >= 1; m >>= 1) mx = fmaxf(mx, __shfl_xor(mx, m));
                float p = expf(sc - mx);
                float sum = p;
#pragma unroll
                for (int m = 32; m >= 1; m >>= 1) sum += __shfl_xor(sum, m);
                sal[tid] = p / sum;
            }
            __syncthreads();

            // ctx
            for (int hh2 = tid; hh2 < Hc; hh2 += 256) {
                float e0 = 0.f, e1 = 0.f, e2 = 0.f, e3 = 0.f;
                for (int s = 0; s < Sc; s += 4) {
                    e0 = fmaf(sal[s + 0], enc[((size_t)(s + 0) * Bc + b2) * Hc + hh2], e0);
                    e1 = fmaf(sal[s + 1], enc[((size_t)(s + 1) * Bc + b2) * Hc + hh2], e1);
                    e2 = fmaf(sal[s + 2], enc[((size_t)(s + 2) * Bc + b2) * Hc + hh2], e2);
                    e3 = fmaf(sal[s + 3], enc[((size_t)(s + 3) * Bc + b2) * Hc + hh2], e3);
                }
                shc[Hc + hh2] = ((e0 + e1) + (e2 + e3));
            }
            __syncthreads();

            // W_c: 4 threads per output k, 256-wide chunk each
            {
                int kl = tid >> 2, r = tid & 3;
                int k = g * 64 + kl;
                const float* wrow = W_c + (size_t)k * (2 * Hc) + r * 256;
                const float* xv = shc + r * 256;
                float p0 = 0.f, p1 = 0.f, p2 = 0.f, p3 = 0.f;
                for (int i = 0; i < 256; i += 16) {
                    p0 += dot4(xv + i, wrow + i);
                    p1 += dot4(xv + i + 4, wrow + i + 4);
                    p2 += dot4(xv + i + 8, wrow + i + 8);
                    p3 += dot4(xv + i + 12, wrow + i + 12);
                }
                float p = ((p0 + p1) + (p2 + p3));
                p += __shfl_xor(p, 1);
                p += __shfl_xor(p, 2);
                if (r == 0)
                    ah_all[(size_t)(t + 1) * BH + b2 * Hc + k] = tanhf(p + b_c[k]);
            }
        }
        if (t < Tc - 2) GBAR((2 * t + 2) * NBLK);
    }
}

// Batched logits GEMM: out[m][n] = ah[m] . W_o[n] + b_o[n]  (M=992,K=512,N=32000)
__global__ __launch_bounds__(256) void k_biglogits(const float* __restrict__ A,
                                                   const float* __restrict__ W_o,
                                                   const float* __restrict__ b_o,
                                                   float* __restrict__ out) {
    __shared__ float At[32][128];
    __shared__ float Bt[32][128];
    int tid = threadIdx.x;
    int n_base = blockIdx.x * 128;
    int m_base = blockIdx.y * 128;
    int tn = tid & 15, tm = tid >> 4;

    float acc[2][4][2][4];
#pragma unroll
    for (int mg = 0; mg < 2; ++mg)
#pragma unroll
        for (int mi = 0; mi < 4; ++mi)
#pragma unroll
            for (int ng = 0; ng < 2; ++ng)
#pragma unroll
                for (int ni = 0; ni < 4; ++ni) acc[mg][mi][ng][ni] = 0.0f;

    int srow = tid >> 1;
    int koff = (tid & 1) * 16;
    int gm = m_base + srow;
    const float* arow = A + (size_t)gm * Hc + koff;
    const float* brow = W_o + (size_t)(n_base + srow) * Hc + koff;

    for (int kc = 0; kc < Hc; kc += 32) {
        float av[16], bv[16];
#pragma unroll
        for (int i = 0; i < 4; ++i) {
            float4 t4 = (gm < Mtot) ? *(const float4*)(arow + kc + i * 4)
                                    : make_float4(0.f, 0.f, 0.f, 0.f);
            av[i * 4 + 0] = t4.x; av[i * 4 + 1] = t4.y; av[i * 4 + 2] = t4.z; av[i * 4 + 3] = t4.w;
            float4 u4 = *(const float4*)(brow + kc + i * 4);
            bv[i * 4 + 0] = u4.x; bv[i * 4 + 1] = u4.y; bv[i * 4 + 2] = u4.z; bv[i * 4 + 3] = u4.w;
        }
        __syncthreads();
#pragma unroll
        for (int i = 0; i < 16; ++i) {
            At[koff + i][srow] = av[i];
            Bt[koff + i][srow] = bv[i];
        }
        __syncthreads();
#pragma unroll
        for (int k = 0; k < 32; ++k) {
            float4 a0 = *(const float4*)&At[k][tm * 4];
            float4 a1 = *(const float4*)&At[k][64 + tm * 4];
            float4 b0 = *(const float4*)&Bt[k][tn * 4];
            float4 b1 = *(const float4*)&Bt[k][64 + tn * 4];
            float am[2][4] = {{a0.x, a0.y, a0.z, a0.w}, {a1.x, a1.y, a1.z, a1.w}};
            float bn[2][4] = {{b0.x, b0.y, b0.z, b0.w}, {b1.x, b1.y, b1.z, b1.w}};
#pragma unroll
            for (int mg = 0; mg < 2; ++mg)
#pragma unroll
                for (int mi = 0; mi < 4; ++mi)
#pragma unroll
                    for (int ng = 0; ng < 2; ++ng)
#pragma unroll
                        for (int ni = 0; ni < 4; ++ni)
                            acc[mg][mi][ng][ni] = fmaf(am[mg][mi], bn[ng][ni], acc[mg][mi][ng][ni]);
        }
        __syncthreads();
    }

#pragma unroll
    for (int ng = 0; ng < 2; ++ng) {
        int n = n_base + ng * 64 + tn * 4;
        float4 bo = *(const float4*)(b_o + n);
#pragma unroll
        for (int mg = 0; mg < 2; ++mg)
#pragma unroll
            for (int mi = 0; mi < 4; ++mi) {
                int m = m_base + mg * 64 + tm * 4 + mi;
                if (m < Mtot) {
                    float4 v;
                    v.x = acc[mg][mi][ng][0] + bo.x;
                    v.y = acc[mg][mi][ng][1] + bo.y;
                    v.z = acc[mg][mi][ng][2] + bo.z;
                    v.w = acc[mg][mi][ng][3] + bo.w;
                    *(float4*)(out + (size_t)m * Vc + n) = v;
                }
            }
    }
}

// Online (single-read) argmax + logsumexp, then subtract in place.
__global__ __launch_bounds__(256) void k_reduce_norm(float* __restrict__ out,
                                                     float* __restrict__ words) {
    int m = blockIdx.x, tid = threadIdx.x;
    float* row = out + (size_t)m * Vc;
    float mx = -INFINITY, l = 0.0f;
    int mi = 0;
    for (int v = tid; v < Vc; v += 256) {
        float x = row[v];
        if (x > mx) {
            l = l * expf(mx - x) + 1.0f;
            mx = x; mi = v;
        } else {
            l += expf(x - mx);
        }
    }
    __shared__ float smx[256];
    __shared__ int smi[256];
    __shared__ float ssum[256];
    smx[tid] = mx; smi[tid] = mi;
    __syncthreads();
    for (int off = 128; off; off >>= 1) {
        if (tid < off) {
            float o = smx[tid + off]; int oi = smi[tid + off];
            if (o > smx[tid] || (o == smx[tid] && oi < smi[tid])) { smx[tid] = o; smi[tid] = oi; }
        }
        __syncthreads();
    }
    float gmx = smx[0];
    ssum[tid] = l * expf(mx - gmx);
    __syncthreads();
    for (int off = 128; off; off >>= 1) {
        if (tid < off) ssum[tid] += ssum[tid + off];
        __syncthreads();
    }
    float lse = gmx + logf(ssum[0]);
    __syncthreads();
    for (int v = tid; v < Vc; v += 256) row[v] -= lse;
    if (tid == 0) words[m] = (float)smi[0];
}

extern "C" void kernel_launch(void* const* d_in, const int* in_sizes, int n_in,
                              void* d_out, int out_size, void* d_ws, size_t ws_size,
                              hipStream_t stream) {
    const int*   tgt     = (const int*)d_in[0];
    const int*   len_src = (const int*)d_in[1];
    const float* enc     = (const float*)d_in[2];
    const float* h0      = (const float*)d_in[3];
    const float* c0      = (const float*)d_in[4];
    const float* emb     = (const float*)d_in[5];
    const float* W_ih    = (const float*)d_in[6];
    const float* W_hh    = (const float*)d_in[7];
    const float* b_ih    = (const float*)d_in[8];
    const float* b_hh    = (const float*)d_in[9];
    const float* W_a     = (const float*)d_in[10];
    const float* W_c     = (const float*)d_in[11];
    const float* b_c     = (const float*)d_in[12];
    const float* W_o     = (const float*)d_in[13];
    const float* b_o     = (const float*)d_in[14];

    float* out = (float*)d_out;
    float* ws = (float*)d_ws;

    float* proj   = ws;                                   // 1,048,576 floats
    float* hG     = proj + (size_t)Bc * Sc * Hc;          // 2 * BH
    float* ah_all = hG + 2 * BH;                          // 32 * BH (slot0 = zeros)
    unsigned* bar = (unsigned*)(ah_all + 32 * BH);        // 64 uints
    float* out_words = out + (size_t)(Tc - 1) * Bc * Vc;

    k_init<<<64, 256, 0, stream>>>(h0, hG, ah_all, bar);
    {
        dim3 g(Hc / 256, Sc / 8, Bc);
        k_proj<<<g, 256, 0, stream>>>(W_a, enc, proj);
    }
    k_loop<<<NBLK, 256, 0, stream>>>(tgt, emb, W_ih, W_hh, b_ih, b_hh, proj, enc,
                                     len_src, W_c, b_c, c0, hG, ah_all, bar);
    {
        dim3 g(Vc / 128, (Mtot + 127) / 128);             // 250 x 8
        k_biglogits<<<g, 256, 0, stream>>>(ah_all + BH, W_o, b_o, out);
    }
    k_reduce_norm<<<Mtot, 256, 0, stream>>>(out, out_words);
}